// Round 3
// baseline (1013.499 us; speedup 1.0000x reference)
//
#include <hip/hip_runtime.h>

// Problem constants (from reference)
#define NN  100000   // nodes
#define DF  128      // feature dim per table
#define KD  512      // input dim = 4*DF
#define HD  64       // hidden dim
#define NS  250000   // samples
#define TILE 32      // samples per block

// Block: 256 threads = 4 waves. Each block handles TILE=32 samples:
//   stage h rows (32 x 512 fp32 = 64 KB LDS) via coalesced float4 gathers,
//   then each wave computes 8 samples: lane -> sample (lane>>3), hidden
//   units (lane&7)*8..+7. W1 read from global (L2-hot, each dwordx4 shared
//   by 8 sample groups).
//
// LESSONS (R1/R2):
//  - train_sample is int32 on device (harness converts; reading as int64
//    page-faulted -> core dump in R2).
//  - NS % TILE == 16: must launch ceil(NS/TILE)=7813 blocks, clamp the
//    gather sample index, and predicate the store (R1 launched 7812 and
//    left 16 samples unwritten -> absmax 2.70).
__global__ __launch_bounds__(256) void mlp_fused_kernel(
    const float* __restrict__ in1,
    const float* __restrict__ in2,
    const int*   __restrict__ ts,     // train_sample, int32 on device
    const float* __restrict__ w1,     // (512, 64) row-major
    const float* __restrict__ b1,     // (64)
    const float* __restrict__ w2,     // (64, 1)
    float* __restrict__ out)          // (250000)
{
    __shared__ float hbuf[TILE * KD];   // 65536 bytes

    const int t  = threadIdx.x;
    const int s0 = blockIdx.x * TILE;

    // ---- gather: 32 samples * 128 float4 = 4096 float4, 16 per thread ----
    #pragma unroll
    for (int i = 0; i < 16; ++i) {
        const int idx = i * 256 + t;    // 0..4095
        const int s   = idx >> 7;       // sample within tile
        const int q   = idx & 127;      // float4 index within the 512-float h row
        const int seg = q >> 5;         // 0: in1[src] 1: in1[dst] 2: in2[src] 3: in2[dst]
        const int off = q & 31;         // float4 within the 128-float node row
        const int sg  = min(s0 + s, NS - 1);            // clamp for tail block
        const int node = ts[sg * 2 + (seg & 1)];
        const float* base = (seg < 2) ? in1 : in2;
        const float4 v = *(const float4*)(base + (long long)node * DF + off * 4);
        *(float4*)(&hbuf[s * KD + q * 4]) = v;
    }
    __syncthreads();

    // ---- compute ----
    const int lane = t & 63;
    const int wv   = t >> 6;
    const int s    = wv * 8 + (lane >> 3);   // sample 0..31
    const int j0   = (lane & 7) * 8;         // hidden base 0..56

    float acc[8];
    #pragma unroll
    for (int r = 0; r < 8; ++r) acc[r] = 0.f;

    const float* hrow = &hbuf[s * KD];

    #pragma unroll 2
    for (int k = 0; k < KD; k += 4) {
        const float4 hv = *(const float4*)(hrow + k);   // broadcast within 8-lane group
        #pragma unroll
        for (int kk = 0; kk < 4; ++kk) {
            const float h = (&hv.x)[kk];
            const float4 wa = *(const float4*)(w1 + (k + kk) * HD + j0);
            const float4 wb = *(const float4*)(w1 + (k + kk) * HD + j0 + 4);
            acc[0] += h * wa.x; acc[1] += h * wa.y;
            acc[2] += h * wa.z; acc[3] += h * wa.w;
            acc[4] += h * wb.x; acc[5] += h * wb.y;
            acc[6] += h * wb.z; acc[7] += h * wb.w;
        }
    }

    // ---- epilogue: relu(acc + b1) . w2, reduce over the 8 lanes of the group ----
    float partial = 0.f;
    #pragma unroll
    for (int r = 0; r < 8; ++r) {
        float x = acc[r] + b1[j0 + r];
        x = x > 0.f ? x : 0.f;
        partial += x * w2[j0 + r];
    }
    partial += __shfl_xor(partial, 1);
    partial += __shfl_xor(partial, 2);
    partial += __shfl_xor(partial, 4);
    if ((lane & 7) == 0 && (s0 + s) < NS) out[s0 + s] = partial;
}

extern "C" void kernel_launch(void* const* d_in, const int* in_sizes, int n_in,
                              void* d_out, int out_size, void* d_ws, size_t ws_size,
                              hipStream_t stream) {
    const float* in1 = (const float*)d_in[0];
    const float* in2 = (const float*)d_in[1];
    const int*   ts  = (const int*)  d_in[2];
    const float* w1  = (const float*)d_in[3];
    const float* b1  = (const float*)d_in[4];
    const float* w2  = (const float*)d_in[5];
    float* out = (float*)d_out;

    const int nblocks = (NS + TILE - 1) / TILE;   // 7813 (last block clamped)
    mlp_fused_kernel<<<nblocks, 256, 0, stream>>>(in1, in2, ts, w1, b1, w2, out);
}

// Round 4
// 845.896 us; speedup vs baseline: 1.1981x; 1.1981x over previous
//
#include <hip/hip_runtime.h>

// Problem constants (from reference)
#define NN  100000   // nodes
#define DF  128      // feature dim per table
#define KD  512      // input dim = 4*DF
#define HD  64       // hidden dim
#define NS  250000   // samples

// ---------------------------------------------------------------------------
// Algebraic restructure: relu is the only nonlinearity, so
//   h@W1 = in1[src]@W1a + in1[dst]@W1b + in2[src]@W1c + in2[dst]@W1d
// where W1a=w1[0:128], W1b=w1[128:256], W1c=w1[256:384], W1d=w1[384:512].
// Phase 1 (dense GEMM): Pa[n] = in1[n] @ [W1a|W1b]  (100000 x 128)
//                       Pb[n] = in2[n] @ [W1c|W1d]  (100000 x 128)
//   -> 3.3 GMACs total (vs 8.2 GMACs for the per-sample formulation).
// Phase 2 (per-sample, memory-bound): for sample s with (src,dst):
//   x[j] = relu(Pa[src][j] + Pa[dst][64+j] + Pb[src][j] + Pb[dst][64+j] + b1[j])
//   out[s] = sum_j x[j]*w2[j]
// P tables (102.4 MB) live in d_ws and fit in the 256 MB L3.
//
// LESSONS (R1-R3): train_sample is int32 on device; R3 was latency-bound
// (VALUBusy 14%, occupancy 22% @ 2 blocks/CU from 64KB LDS, 4.8e7 LDS
// bank-conflict cycles from 512-float row stride).
// ---------------------------------------------------------------------------

#define MT   32      // rows per phase-1 block
#define HPAD 132     // 128 + 4: row stride in LDS floats, breaks bank aliasing

// Phase 1: grid = 6250 (3125 blocks per table), block = 256.
// Each block: stage MT=32 input rows in LDS (padded), compute a 32x128 tile
// of P. Lane layout: row = wave*8 + (lane>>3), cols j0=(lane&7)*16 .. +15.
__global__ __launch_bounds__(256) void node_gemm_kernel(
    const float* __restrict__ in1,
    const float* __restrict__ in2,
    const float* __restrict__ w1,     // (512, 64) row-major
    float* __restrict__ P)            // [2][NN][128] in d_ws
{
    __shared__ float hbuf[MT * HPAD];   // 16896 bytes

    const int t     = threadIdx.x;
    const int table = (blockIdx.x >= NN / MT) ? 1 : 0;
    const int m0    = (blockIdx.x - table * (NN / MT)) * MT;
    const float* in = table ? in2 : in1;
    const int koff  = table * 256;      // w1 row offset: in2 uses rows 256..511

    // ---- stage 32 rows x 128 floats (coalesced float4) ----
    #pragma unroll
    for (int i = 0; i < 4; ++i) {
        const int idx = i * 256 + t;        // 0..1023
        const int r   = idx >> 5;           // row 0..31
        const int q   = idx & 31;           // float4 0..31
        const float4 v = *(const float4*)(in + (size_t)(m0 + r) * DF + q * 4);
        *(float4*)(&hbuf[r * HPAD + q * 4]) = v;
    }
    __syncthreads();

    // ---- compute ----
    const int lane = t & 63;
    const int wv   = t >> 6;
    const int row  = wv * 8 + (lane >> 3);   // 0..31
    const int j0   = (lane & 7) * 16;        // output col base, 0..112
    const int half = j0 >> 6;                // 0 -> W1{a,c}, 1 -> W1{b,d}
    const int jc   = j0 & 63;                // col within the 64-wide w1

    const float* wbase = w1 + (size_t)(koff + half * 128) * HD + jc;

    float acc[16];
    #pragma unroll
    for (int r = 0; r < 16; ++r) acc[r] = 0.f;

    const float* hrow = &hbuf[row * HPAD];

    for (int k = 0; k < DF; k += 4) {
        const float4 hv = *(const float4*)(hrow + k);   // conflict-free (HPAD)
        #pragma unroll
        for (int kk = 0; kk < 4; ++kk) {
            const float h = (&hv.x)[kk];
            const float* wr = wbase + (size_t)(k + kk) * HD;
            const float4 wv0 = *(const float4*)(wr);
            const float4 wv1 = *(const float4*)(wr + 4);
            const float4 wv2 = *(const float4*)(wr + 8);
            const float4 wv3 = *(const float4*)(wr + 12);
            acc[ 0] += h * wv0.x; acc[ 1] += h * wv0.y;
            acc[ 2] += h * wv0.z; acc[ 3] += h * wv0.w;
            acc[ 4] += h * wv1.x; acc[ 5] += h * wv1.y;
            acc[ 6] += h * wv1.z; acc[ 7] += h * wv1.w;
            acc[ 8] += h * wv2.x; acc[ 9] += h * wv2.y;
            acc[10] += h * wv2.z; acc[11] += h * wv2.w;
            acc[12] += h * wv3.x; acc[13] += h * wv3.y;
            acc[14] += h * wv3.z; acc[15] += h * wv3.w;
        }
    }

    float* po = P + (size_t)table * NN * 128 + (size_t)(m0 + row) * 128 + j0;
    *(float4*)(po)      = make_float4(acc[ 0], acc[ 1], acc[ 2], acc[ 3]);
    *(float4*)(po + 4)  = make_float4(acc[ 4], acc[ 5], acc[ 6], acc[ 7]);
    *(float4*)(po + 8)  = make_float4(acc[ 8], acc[ 9], acc[10], acc[11]);
    *(float4*)(po + 12) = make_float4(acc[12], acc[13], acc[14], acc[15]);
}

// Phase 2: grid = 15625 (exact: x16 samples = 250000), block = 256.
// 16 lanes per sample; lane l covers cols j = 4l..4l+3 of the hidden vector.
__global__ __launch_bounds__(256) void edge_mlp_kernel(
    const float* __restrict__ P,
    const int*   __restrict__ ts,     // train_sample, int32
    const float* __restrict__ b1,     // (64)
    const float* __restrict__ w2,     // (64)
    float* __restrict__ out)          // (250000)
{
    const int t = threadIdx.x;
    const int s = blockIdx.x * 16 + (t >> 4);
    const int l = t & 15;
    const int j = l * 4;

    const int2 e = ((const int2*)ts)[s];    // (src, dst)
    const float* Pa = P;
    const float* Pb = P + (size_t)NN * 128;

    const float4 a0 = *(const float4*)(Pa + (size_t)e.x * 128 + j);
    const float4 a1 = *(const float4*)(Pa + (size_t)e.y * 128 + 64 + j);
    const float4 c0 = *(const float4*)(Pb + (size_t)e.x * 128 + j);
    const float4 c1 = *(const float4*)(Pb + (size_t)e.y * 128 + 64 + j);
    const float4 bb = *(const float4*)(b1 + j);
    const float4 ww = *(const float4*)(w2 + j);

    float p = 0.f;
    {
        float x;
        x = a0.x + a1.x + c0.x + c1.x + bb.x; x = x > 0.f ? x : 0.f; p += x * ww.x;
        x = a0.y + a1.y + c0.y + c1.y + bb.y; x = x > 0.f ? x : 0.f; p += x * ww.y;
        x = a0.z + a1.z + c0.z + c1.z + bb.z; x = x > 0.f ? x : 0.f; p += x * ww.z;
        x = a0.w + a1.w + c0.w + c1.w + bb.w; x = x > 0.f ? x : 0.f; p += x * ww.w;
    }
    p += __shfl_xor(p, 1);
    p += __shfl_xor(p, 2);
    p += __shfl_xor(p, 4);
    p += __shfl_xor(p, 8);
    if (l == 0) out[s] = p;
}

extern "C" void kernel_launch(void* const* d_in, const int* in_sizes, int n_in,
                              void* d_out, int out_size, void* d_ws, size_t ws_size,
                              hipStream_t stream) {
    const float* in1 = (const float*)d_in[0];
    const float* in2 = (const float*)d_in[1];
    const int*   ts  = (const int*)  d_in[2];
    const float* w1  = (const float*)d_in[3];
    const float* b1  = (const float*)d_in[4];
    const float* w2  = (const float*)d_in[5];
    float* out = (float*)d_out;
    float* P   = (float*)d_ws;        // needs 2*100000*128*4 = 102.4 MB

    node_gemm_kernel<<<2 * (NN / MT), 256, 0, stream>>>(in1, in2, w1, P);
    edge_mlp_kernel<<<NS / 16, 256, 0, stream>>>(P, ts, b1, w2, out);
}

// Round 5
// 181.187 us; speedup vs baseline: 5.5937x; 4.6686x over previous
//
#include <hip/hip_runtime.h>
#include <hip/hip_bf16.h>

// Problem constants (from reference)
#define NN  100000   // nodes
#define DF  128      // feature dim per table
#define HD  64       // hidden dim
#define NS  250000   // samples

// ---------------------------------------------------------------------------
// Algebra (R4): h@W1 = in1[src]@W1a + in1[dst]@W1b + in2[src]@W1c + in2[dst]@W1d
//   Phase 1: P[T][n][0:128] = inT[n] @ [W1x|W1y]   (T=0: a,b; T=1: c,d)
//   Phase 2: x = relu(Pa[src][0:64]+Pa[dst][64:]+Pb[src][0:64]+Pb[dst][64:]+b1)
//            out = x . w2
// R4 post-mortem: phase-1 was VMEM-latency bound re-loading W1 from global
// (VALUBusy 6.6%). R5: bf16 MFMA (16x16x32), W1 pre-packed in B-fragment
// order by a prep kernel and held in registers; A staged fp32->bf16 into LDS
// in A-fragment order. fp32 accumulate; threshold is bf16-floored (0.12).
//
// Verified MFMA layouts (gfx950, learn_hip m89/m91/m120):
//   A-frag: A[m=lane&15][k=(lane>>4)*8+j], j=0..7 contiguous in reg
//   B-frag: B[n=lane&15][k=(lane>>4)*8+j]
//   C/D   : col=lane&15, row=(lane>>4)*4+reg
// LESSONS (R1-R3): train_sample is int32 on device; 250000%32!=0 tail care.
// ---------------------------------------------------------------------------

typedef __attribute__((ext_vector_type(8))) short bfrag;   // 8 bf16 = 4 VGPRs
typedef __attribute__((ext_vector_type(4))) float ffrag;   // 4 fp32 acc

__device__ __forceinline__ unsigned short bf16bits(float f) {
    __hip_bfloat16 b = __float2bfloat16(f);   // RNE
    return *(unsigned short*)&b;
}
__device__ __forceinline__ unsigned pack2(float a, float b) {
    return (unsigned)bf16bits(a) | ((unsigned)bf16bits(b) << 16);
}

// ---- prep: pack w1 (512x64 fp32) into B-fragment-ordered bf16 table ----
// Bf[T][tn][ks][lane][j] : B[k][n] with n=tn*16+(lane&15), k=ks*32+(lane>>4)*8+j
//   B[k][n] = w1[T*256 + (n>=64)*128 + k][n&63]
// 2*8*4*64 = 4096 threads, each writes one 16-byte fragment.
__global__ __launch_bounds__(256) void prep_w1_kernel(
    const float* __restrict__ w1, unsigned short* __restrict__ Bf)
{
    const int gid  = blockIdx.x * 256 + threadIdx.x;   // 0..4095
    const int lane = gid & 63;
    const int ks   = (gid >> 6) & 3;
    const int tn   = (gid >> 8) & 7;
    const int T    = gid >> 11;

    const int n     = tn * 16 + (lane & 15);
    const int kbase = ks * 32 + (lane >> 4) * 8;
    const int row0  = T * 256 + ((n >= 64) ? 128 : 0);
    const int col   = n & 63;

    float v[8];
    #pragma unroll
    for (int j = 0; j < 8; ++j) v[j] = w1[(size_t)(row0 + kbase + j) * HD + col];

    uint4 u;
    u.x = pack2(v[0], v[1]); u.y = pack2(v[2], v[3]);
    u.z = pack2(v[4], v[5]); u.w = pack2(v[6], v[7]);
    *(uint4*)(Bf + (size_t)gid * 8) = u;
}

// ---- phase 1: MFMA node GEMM ----
// grid = 12500 (2 tables x 6250 blocks of 16 rows), block = 256 (4 waves).
// Block: 16 rows x 128 cols, K=128. Wave w covers col tiles {2w, 2w+1}.
__global__ __launch_bounds__(256) void node_gemm_mfma(
    const float* __restrict__ in1,
    const float* __restrict__ in2,
    const unsigned short* __restrict__ Bf,   // packed w1 fragments
    float* __restrict__ P)                   // [2][NN][128]
{
    __shared__ unsigned short albs[2048];    // A frags: [ks][lane][j] bf16, 4 KB

    const int t  = threadIdx.x;
    const int T  = (blockIdx.x >= NN / 16) ? 1 : 0;
    const int m0 = (blockIdx.x - T * (NN / 16)) * 16;
    const float* in = T ? in2 : in1;

    // ---- stage A: 16 rows x 128 k, fp32 -> bf16, fragment order ----
    // thread t: row r=t>>4, k-range [qq*8, qq*8+8) with qq=t&15
    //   -> ks=qq>>2, quad=qq&3, lane_a=quad*16+r, j=0..7 (one full fragment)
    {
        const int r    = t >> 4;
        const int qq   = t & 15;
        const int ks   = qq >> 2;
        const int quad = qq & 3;
        const int la   = quad * 16 + r;
        const float* src = in + (size_t)(m0 + r) * DF + qq * 8;
        const float4 f0 = *(const float4*)(src);
        const float4 f1 = *(const float4*)(src + 4);
        uint4 u;
        u.x = pack2(f0.x, f0.y); u.y = pack2(f0.z, f0.w);
        u.z = pack2(f1.x, f1.y); u.w = pack2(f1.z, f1.w);
        *(uint4*)(&albs[ks * 512 + la * 8]) = u;
    }
    __syncthreads();

    const int lane = t & 63;
    const int w    = t >> 6;

    // ---- b-frags: 2 tiles x 4 ksteps, loaded once from global (L2-hot) ----
    bfrag bf[2][4];
    #pragma unroll
    for (int ti = 0; ti < 2; ++ti) {
        const int tn = w * 2 + ti;
        #pragma unroll
        for (int ks = 0; ks < 4; ++ks) {
            const size_t off = ((((size_t)T * 8 + tn) * 4 + ks) * 64 + lane) * 8;
            bf[ti][ks] = *(const bfrag*)(Bf + off);
        }
    }

    // ---- a-frags from LDS ----
    bfrag af[4];
    #pragma unroll
    for (int ks = 0; ks < 4; ++ks)
        af[ks] = *(const bfrag*)(&albs[ks * 512 + lane * 8]);

    // ---- MFMA ----
    ffrag acc[2] = {{0.f, 0.f, 0.f, 0.f}, {0.f, 0.f, 0.f, 0.f}};
    #pragma unroll
    for (int ks = 0; ks < 4; ++ks) {
        acc[0] = __builtin_amdgcn_mfma_f32_16x16x32_bf16(af[ks], bf[0][ks], acc[0], 0, 0, 0);
        acc[1] = __builtin_amdgcn_mfma_f32_16x16x32_bf16(af[ks], bf[1][ks], acc[1], 0, 0, 0);
    }

    // ---- epilogue: C/D layout col=lane&15, row=(lane>>4)*4+reg ----
    const int col = lane & 15;
    const int rq  = lane >> 4;
    float* Pb = P + (size_t)T * NN * 128 + (size_t)m0 * 128;
    #pragma unroll
    for (int ti = 0; ti < 2; ++ti) {
        const int nb = (w * 2 + ti) * 16 + col;
        #pragma unroll
        for (int reg = 0; reg < 4; ++reg)
            Pb[(size_t)(rq * 4 + reg) * 128 + nb] = acc[ti][reg];
    }
}

// ---- phase 2: per-sample gather + relu + w2 (unchanged from R4) ----
__global__ __launch_bounds__(256) void edge_mlp_kernel(
    const float* __restrict__ P,
    const int*   __restrict__ ts,     // train_sample, int32
    const float* __restrict__ b1,     // (64)
    const float* __restrict__ w2,     // (64)
    float* __restrict__ out)          // (250000)
{
    const int t = threadIdx.x;
    const int s = blockIdx.x * 16 + (t >> 4);
    const int l = t & 15;
    const int j = l * 4;

    const int2 e = ((const int2*)ts)[s];
    const float* Pa = P;
    const float* Pbt = P + (size_t)NN * 128;

    const float4 a0 = *(const float4*)(Pa  + (size_t)e.x * 128 + j);
    const float4 a1 = *(const float4*)(Pa  + (size_t)e.y * 128 + 64 + j);
    const float4 c0 = *(const float4*)(Pbt + (size_t)e.x * 128 + j);
    const float4 c1 = *(const float4*)(Pbt + (size_t)e.y * 128 + 64 + j);
    const float4 bb = *(const float4*)(b1 + j);
    const float4 ww = *(const float4*)(w2 + j);

    float p = 0.f;
    float x;
    x = a0.x + a1.x + c0.x + c1.x + bb.x; x = x > 0.f ? x : 0.f; p += x * ww.x;
    x = a0.y + a1.y + c0.y + c1.y + bb.y; x = x > 0.f ? x : 0.f; p += x * ww.y;
    x = a0.z + a1.z + c0.z + c1.z + bb.z; x = x > 0.f ? x : 0.f; p += x * ww.z;
    x = a0.w + a1.w + c0.w + c1.w + bb.w; x = x > 0.f ? x : 0.f; p += x * ww.w;

    p += __shfl_xor(p, 1);
    p += __shfl_xor(p, 2);
    p += __shfl_xor(p, 4);
    p += __shfl_xor(p, 8);
    if (l == 0) out[s] = p;
}

extern "C" void kernel_launch(void* const* d_in, const int* in_sizes, int n_in,
                              void* d_out, int out_size, void* d_ws, size_t ws_size,
                              hipStream_t stream) {
    const float* in1 = (const float*)d_in[0];
    const float* in2 = (const float*)d_in[1];
    const int*   ts  = (const int*)  d_in[2];
    const float* w1  = (const float*)d_in[3];
    const float* b1  = (const float*)d_in[4];
    const float* w2  = (const float*)d_in[5];
    float* out = (float*)d_out;

    float* P = (float*)d_ws;                       // 2*100000*128*4 = 102.4 MB
    const size_t Pbytes = (size_t)2 * NN * 128 * sizeof(float);
    // 64 KB of packed-w1 fragments: after P if d_ws has room, else borrow the
    // front of d_out (1 MB; phase-2 overwrites every element afterwards).
    unsigned short* Bf;
    if (ws_size >= Pbytes + 65536)
        Bf = (unsigned short*)((char*)d_ws + Pbytes);
    else
        Bf = (unsigned short*)d_out;

    prep_w1_kernel<<<16, 256, 0, stream>>>(w1, Bf);
    node_gemm_mfma<<<2 * (NN / 16), 256, 0, stream>>>(in1, in2, Bf, P);
    edge_mlp_kernel<<<NS / 16, 256, 0, stream>>>(P, ts, b1, w2, out);
}

// Round 6
// 158.666 us; speedup vs baseline: 6.3876x; 1.1419x over previous
//
#include <hip/hip_runtime.h>
#include <hip/hip_bf16.h>

// Problem constants (from reference)
#define NN  100000   // nodes
#define DF  128      // feature dim per table
#define HD  64       // hidden dim
#define NS  250000   // samples

// ---------------------------------------------------------------------------
// R6 algebra: out[s] = w2 . relu(u[src] + v[dst] + b1), where
//   u[n] = in1[n]@W1a + in2[n]@W1c   (W1a=w1[0:128],   W1c=w1[256:384])
//   v[n] = in1[n]@W1b + in2[n]@W1d   (W1b=w1[128:256], W1d=w1[384:512])
// Phase 1 is ONE GEMM: Pn = [in1|in2] @ B, M=100000 K=256 N=128,
//   B[k][n] = w1[(k>=128)*256 + (n>=64)*128 + (k&127)][n&63]
//   Pn[n][0:64]=u[n], Pn[n][64:128]=v[n], stored bf16 (25.6 MB, L3-resident).
// Phase 2 reads 2 half-rows (256 B) per sample instead of R5's 4 (1 KB fp32).
//
// Verified MFMA layouts (gfx950, learn_hip m89/m91):
//   A-frag: A[m=lane&15][k=(lane>>4)*8+j]   B-frag: B[n=lane&15][k=...]
//   C/D   : col=lane&15, row=(lane>>4)*4+reg
// LESSONS: train_sample is int32 on device; R5 phase-1 was traffic-bound
// (154 MB @ 3 TB/s), so R6 cuts write bytes 4x and phase-2 read bytes 4x.
// ---------------------------------------------------------------------------

typedef __attribute__((ext_vector_type(8))) short bfrag;   // 8 bf16 = 4 VGPRs
typedef __attribute__((ext_vector_type(4))) float ffrag;   // 4 fp32 acc

__device__ __forceinline__ unsigned short bf16bits(float f) {
    __hip_bfloat16 b = __float2bfloat16(f);   // RNE
    return *(unsigned short*)&b;
}
__device__ __forceinline__ unsigned pack2(float a, float b) {
    return (unsigned)bf16bits(a) | ((unsigned)bf16bits(b) << 16);
}
__device__ __forceinline__ float bflo(unsigned u) {
    union { unsigned i; float f; } c; c.i = u << 16; return c.f;
}
__device__ __forceinline__ float bfhi(unsigned u) {
    union { unsigned i; float f; } c; c.i = u & 0xffff0000u; return c.f;
}

// ---- prep: pack merged B (256x128) into B-fragment-ordered bf16 table ----
// Bf[tn][ks][lane][j], tn=0..7 (16-col tile), ks=0..7 (32-k step):
//   n = tn*16+(lane&15), k = ks*32+(lane>>4)*8+j
// 8*8*64 = 4096 threads, one 16-byte fragment each.
__global__ __launch_bounds__(256) void prep_w1_kernel(
    const float* __restrict__ w1, unsigned short* __restrict__ Bf)
{
    const int gid  = blockIdx.x * 256 + threadIdx.x;   // 0..4095
    const int lane = gid & 63;
    const int ks   = (gid >> 6) & 7;
    const int tn   = gid >> 9;

    const int n     = tn * 16 + (lane & 15);
    const int kbase = ks * 32 + (lane >> 4) * 8;
    const int col   = n & 63;

    uint4 u;
    unsigned p[4];
    #pragma unroll
    for (int jp = 0; jp < 4; ++jp) {
        float v[2];
        #pragma unroll
        for (int h = 0; h < 2; ++h) {
            const int k = kbase + jp * 2 + h;
            const int row = ((k >= 128) ? 256 : 0) + ((n >= 64) ? 128 : 0) + (k & 127);
            v[h] = w1[(size_t)row * HD + col];
        }
        p[jp] = pack2(v[0], v[1]);
    }
    u.x = p[0]; u.y = p[1]; u.z = p[2]; u.w = p[3];
    *(uint4*)(Bf + (size_t)gid * 8) = u;
}

// ---- phase 1: fused MFMA GEMM, M-tile 16, K=256, N=128 ----
// grid = 6250, block = 256 (4 waves). Wave w covers col tiles {2w, 2w+1}.
__global__ __launch_bounds__(256) void node_gemm_mfma(
    const float* __restrict__ in1,
    const float* __restrict__ in2,
    const unsigned short* __restrict__ Bf,
    unsigned short* __restrict__ Pn)         // [NN][128] bf16
{
    __shared__ unsigned short smem[4096];    // 8 KB: A-frags, then reused as C-buf

    const int t  = threadIdx.x;
    const int m0 = blockIdx.x * 16;

    // ---- stage A: 16 rows x 256 k (128 from in1, 128 from in2) -> bf16 frags
    // thread t: row r=t>>4, 16-k chunk qq=t&15 (qq<8: in1, else in2).
    {
        const int r  = t >> 4;
        const int qq = t & 15;
        const float* src = (qq < 8)
            ? in1 + (size_t)(m0 + r) * DF + qq * 16
            : in2 + (size_t)(m0 + r) * DF + (qq - 8) * 16;
        const float4 f0 = *(const float4*)(src);
        const float4 f1 = *(const float4*)(src + 4);
        const float4 f2 = *(const float4*)(src + 8);
        const float4 f3 = *(const float4*)(src + 12);
        // two 8-wide j-groups: g = qq*2+h, ks=g>>2, quad=g&3, la=quad*16+r
        uint4 u0, u1;
        u0.x = pack2(f0.x, f0.y); u0.y = pack2(f0.z, f0.w);
        u0.z = pack2(f1.x, f1.y); u0.w = pack2(f1.z, f1.w);
        u1.x = pack2(f2.x, f2.y); u1.y = pack2(f2.z, f2.w);
        u1.z = pack2(f3.x, f3.y); u1.w = pack2(f3.z, f3.w);
        const int g0 = qq * 2, g1 = qq * 2 + 1;
        *(uint4*)(&smem[(g0 >> 2) * 512 + ((g0 & 3) * 16 + r) * 8]) = u0;
        *(uint4*)(&smem[(g1 >> 2) * 512 + ((g1 & 3) * 16 + r) * 8]) = u1;
    }
    __syncthreads();

    const int lane = t & 63;
    const int w    = t >> 6;

    // ---- b-frags: 2 col tiles x 8 ksteps, loaded once (L2-hot) ----
    bfrag bf[2][8];
    #pragma unroll
    for (int ti = 0; ti < 2; ++ti) {
        const int tn = w * 2 + ti;
        #pragma unroll
        for (int ks = 0; ks < 8; ++ks)
            bf[ti][ks] = *(const bfrag*)(Bf + ((size_t)(tn * 8 + ks) * 64 + lane) * 8);
    }

    // ---- a-frags from LDS ----
    bfrag af[8];
    #pragma unroll
    for (int ks = 0; ks < 8; ++ks)
        af[ks] = *(const bfrag*)(&smem[ks * 512 + lane * 8]);

    // ---- MFMA: 16 per wave ----
    ffrag acc[2] = {{0.f, 0.f, 0.f, 0.f}, {0.f, 0.f, 0.f, 0.f}};
    #pragma unroll
    for (int ks = 0; ks < 8; ++ks) {
        acc[0] = __builtin_amdgcn_mfma_f32_16x16x32_bf16(af[ks], bf[0][ks], acc[0], 0, 0, 0);
        acc[1] = __builtin_amdgcn_mfma_f32_16x16x32_bf16(af[ks], bf[1][ks], acc[1], 0, 0, 0);
    }

    // ---- epilogue: acc -> bf16 LDS tile (16x128) -> coalesced stores ----
    __syncthreads();   // all a-frag reads done; safe to reuse smem
    {
        const int col = lane & 15;
        const int rq  = lane >> 4;
        #pragma unroll
        for (int ti = 0; ti < 2; ++ti) {
            const int nc = (w * 2 + ti) * 16 + col;
            #pragma unroll
            for (int reg = 0; reg < 4; ++reg)
                smem[(rq * 4 + reg) * 128 + nc] = bf16bits(acc[ti][reg]);
        }
    }
    __syncthreads();
    {
        const int row = t >> 4;
        const int seg = t & 15;
        const uint4 u = *(const uint4*)(&smem[row * 128 + seg * 8]);
        *(uint4*)(Pn + (size_t)(m0 + row) * 128 + seg * 8) = u;
    }
}

// ---- phase 2: out[s] = w2 . relu(u[src] + v[dst] + b1) ----
// grid = 15625 (x16 samples), block = 256; 16 lanes/sample, 4 cols/lane.
__global__ __launch_bounds__(256) void edge_mlp_kernel(
    const unsigned short* __restrict__ Pn,
    const int*   __restrict__ ts,     // train_sample, int32
    const float* __restrict__ b1,     // (64)
    const float* __restrict__ w2,     // (64)
    float* __restrict__ out)          // (250000)
{
    const int t = threadIdx.x;
    const int s = blockIdx.x * 16 + (t >> 4);
    const int l = t & 15;
    const int j = l * 4;

    const int2 e = ((const int2*)ts)[s];
    const uint2 uu = *(const uint2*)(Pn + (size_t)e.x * 128 + j);
    const uint2 vv = *(const uint2*)(Pn + (size_t)e.y * 128 + 64 + j);
    const float4 bb = *(const float4*)(b1 + j);
    const float4 ww = *(const float4*)(w2 + j);

    float p = 0.f, x;
    x = bflo(uu.x) + bflo(vv.x) + bb.x; x = x > 0.f ? x : 0.f; p += x * ww.x;
    x = bfhi(uu.x) + bfhi(vv.x) + bb.y; x = x > 0.f ? x : 0.f; p += x * ww.y;
    x = bflo(uu.y) + bflo(vv.y) + bb.z; x = x > 0.f ? x : 0.f; p += x * ww.z;
    x = bfhi(uu.y) + bfhi(vv.y) + bb.w; x = x > 0.f ? x : 0.f; p += x * ww.w;

    p += __shfl_xor(p, 1);
    p += __shfl_xor(p, 2);
    p += __shfl_xor(p, 4);
    p += __shfl_xor(p, 8);
    if (l == 0) out[s] = p;
}

extern "C" void kernel_launch(void* const* d_in, const int* in_sizes, int n_in,
                              void* d_out, int out_size, void* d_ws, size_t ws_size,
                              hipStream_t stream) {
    const float* in1 = (const float*)d_in[0];
    const float* in2 = (const float*)d_in[1];
    const int*   ts  = (const int*)  d_in[2];
    const float* w1  = (const float*)d_in[3];
    const float* b1  = (const float*)d_in[4];
    const float* w2  = (const float*)d_in[5];
    float* out = (float*)d_out;

    unsigned short* Pn = (unsigned short*)d_ws;     // 100000*128*2 = 25.6 MB
    const size_t Pbytes = (size_t)NN * 128 * sizeof(unsigned short);
    unsigned short* Bf;                             // 64 KB packed-B fragments
    if (ws_size >= Pbytes + 65536)
        Bf = (unsigned short*)((char*)d_ws + Pbytes);
    else
        Bf = (unsigned short*)d_out;   // phase-2 fully overwrites d_out after

    prep_w1_kernel<<<16, 256, 0, stream>>>(w1, Bf);
    node_gemm_mfma<<<NN / 16, 256, 0, stream>>>(in1, in2, Bf, Pn);
    edge_mlp_kernel<<<NS / 16, 256, 0, stream>>>(Pn, ts, b1, w2, out);
}

// Round 7
// 147.736 us; speedup vs baseline: 6.8602x; 1.0740x over previous
//
#include <hip/hip_runtime.h>
#include <hip/hip_bf16.h>

// Problem constants (from reference)
#define NN  100000   // nodes
#define DF  128      // feature dim per table
#define HD  64       // hidden dim
#define NS  250000   // samples

// ---------------------------------------------------------------------------
// Algebra (R6): out[s] = w2 . relu(u[src] + v[dst] + b1),
//   Pn = [in1|in2] @ B  (M=100000, K=256, N=128), Pn[n][0:64]=u, [64:128]=v
//   B[k][n] = w1[(k>=128)*256 + (n>=64)*128 + (k&127)][n&63], bf16 Pn (25.6MB)
// R6 post-mortem: 16-row blocks latency-bound (1.8 TB/s, MfmaUtil 4.7%).
// R7: 80-row M-tile per block (1250 blocks), B-frags loaded once and reused
// across 5 subtiles; k-outer MFMA loop -> 10 independent acc chains.
// Phase-2: 8 lanes/sample, 16B loads.
//
// Verified MFMA layouts (gfx950, learn_hip m89/m91):
//   A-frag: A[m=lane&15][k=(lane>>4)*8+j]   B-frag: B[n=lane&15][k=...]
//   C/D   : col=lane&15, row=(lane>>4)*4+reg
// LESSONS: train_sample is int32 on device; NS%32=16 -> clamp+predicate.
// ---------------------------------------------------------------------------

typedef __attribute__((ext_vector_type(8))) short bfrag;   // 8 bf16 = 4 VGPRs
typedef __attribute__((ext_vector_type(4))) float ffrag;   // 4 fp32 acc

__device__ __forceinline__ unsigned short bf16bits(float f) {
    __hip_bfloat16 b = __float2bfloat16(f);   // RNE
    return *(unsigned short*)&b;
}
__device__ __forceinline__ unsigned pack2(float a, float b) {
    return (unsigned)bf16bits(a) | ((unsigned)bf16bits(b) << 16);
}
__device__ __forceinline__ float bflo(unsigned u) {
    union { unsigned i; float f; } c; c.i = u << 16; return c.f;
}
__device__ __forceinline__ float bfhi(unsigned u) {
    union { unsigned i; float f; } c; c.i = u & 0xffff0000u; return c.f;
}

// ---- prep: pack merged B (256x128) into B-fragment-ordered bf16 table ----
// Bf[tn][ks][lane][j]: n = tn*16+(lane&15), k = ks*32+(lane>>4)*8+j
__global__ __launch_bounds__(256) void prep_w1_kernel(
    const float* __restrict__ w1, unsigned short* __restrict__ Bf)
{
    const int gid  = blockIdx.x * 256 + threadIdx.x;   // 0..4095
    const int lane = gid & 63;
    const int ks   = (gid >> 6) & 7;
    const int tn   = gid >> 9;

    const int n     = tn * 16 + (lane & 15);
    const int kbase = ks * 32 + (lane >> 4) * 8;
    const int col   = n & 63;

    uint4 u;
    unsigned p[4];
    #pragma unroll
    for (int jp = 0; jp < 4; ++jp) {
        float v[2];
        #pragma unroll
        for (int h = 0; h < 2; ++h) {
            const int k = kbase + jp * 2 + h;
            const int row = ((k >= 128) ? 256 : 0) + ((n >= 64) ? 128 : 0) + (k & 127);
            v[h] = w1[(size_t)row * HD + col];
        }
        p[jp] = pack2(v[0], v[1]);
    }
    u.x = p[0]; u.y = p[1]; u.z = p[2]; u.w = p[3];
    *(uint4*)(Bf + (size_t)gid * 8) = u;
}

// ---- phase 1: MFMA GEMM, 80 rows/block, K=256, N=128 ----
// grid = 1250, block = 256 (4 waves). Wave w covers col tiles {2w, 2w+1},
// all 5 row-subtiles. A-frag LDS: subtile st at smem[st*4096], layout
// [ks][lane][8] shorts (8 KB per subtile, 40 KB total).
__global__ __launch_bounds__(256) void node_gemm_mfma(
    const float* __restrict__ in1,
    const float* __restrict__ in2,
    const unsigned short* __restrict__ Bf,
    unsigned short* __restrict__ Pn)         // [NN][128] bf16
{
    __shared__ unsigned short smem[20480];   // 40 KB

    const int t  = threadIdx.x;
    const int m0 = blockIdx.x * 80;

    // ---- b-frags first (independent of staging; overlaps with A loads) ----
    const int lane = t & 63;
    const int w    = t >> 6;
    bfrag bfr[2][8];
    #pragma unroll
    for (int ti = 0; ti < 2; ++ti) {
        const int tn = w * 2 + ti;
        #pragma unroll
        for (int ks = 0; ks < 8; ++ks)
            bfr[ti][ks] = *(const bfrag*)(Bf + ((size_t)(tn * 8 + ks) * 64 + lane) * 8);
    }

    // ---- stage A: 5 subtiles x (16 rows x 256 k), fp32 -> bf16 frag order --
    // per subtile, thread t: row r=t>>4, 16-k chunk qq=t&15 (qq<8: in1).
    {
        const int r  = t >> 4;
        const int qq = t & 15;
        #pragma unroll
        for (int st = 0; st < 5; ++st) {
            const int row = m0 + st * 16 + r;
            const float* src = (qq < 8)
                ? in1 + (size_t)row * DF + qq * 16
                : in2 + (size_t)row * DF + (qq - 8) * 16;
            const float4 f0 = *(const float4*)(src);
            const float4 f1 = *(const float4*)(src + 4);
            const float4 f2 = *(const float4*)(src + 8);
            const float4 f3 = *(const float4*)(src + 12);
            uint4 u0, u1;
            u0.x = pack2(f0.x, f0.y); u0.y = pack2(f0.z, f0.w);
            u0.z = pack2(f1.x, f1.y); u0.w = pack2(f1.z, f1.w);
            u1.x = pack2(f2.x, f2.y); u1.y = pack2(f2.z, f2.w);
            u1.z = pack2(f3.x, f3.y); u1.w = pack2(f3.z, f3.w);
            const int g0 = qq * 2, g1 = qq * 2 + 1;
            *(uint4*)(&smem[st * 4096 + (g0 >> 2) * 512 + ((g0 & 3) * 16 + r) * 8]) = u0;
            *(uint4*)(&smem[st * 4096 + (g1 >> 2) * 512 + ((g1 & 3) * 16 + r) * 8]) = u1;
        }
    }
    __syncthreads();

    // ---- MFMA: ks-outer, subtile-inner -> 10 independent acc chains ----
    ffrag acc[5][2];
    #pragma unroll
    for (int st = 0; st < 5; ++st) {
        acc[st][0] = (ffrag){0.f, 0.f, 0.f, 0.f};
        acc[st][1] = (ffrag){0.f, 0.f, 0.f, 0.f};
    }
    #pragma unroll
    for (int ks = 0; ks < 8; ++ks) {
        #pragma unroll
        for (int st = 0; st < 5; ++st) {
            const bfrag af = *(const bfrag*)(&smem[st * 4096 + ks * 512 + lane * 8]);
            acc[st][0] = __builtin_amdgcn_mfma_f32_16x16x32_bf16(af, bfr[0][ks], acc[st][0], 0, 0, 0);
            acc[st][1] = __builtin_amdgcn_mfma_f32_16x16x32_bf16(af, bfr[1][ks], acc[st][1], 0, 0, 0);
        }
    }

    // ---- epilogue: acc -> bf16 LDS (80x128 = 20 KB) -> coalesced stores ----
    __syncthreads();
    {
        const int col = lane & 15;
        const int rq  = lane >> 4;
        #pragma unroll
        for (int st = 0; st < 5; ++st) {
            #pragma unroll
            for (int ti = 0; ti < 2; ++ti) {
                const int nc = (w * 2 + ti) * 16 + col;
                #pragma unroll
                for (int reg = 0; reg < 4; ++reg)
                    smem[(st * 16 + rq * 4 + reg) * 128 + nc] = bf16bits(acc[st][ti][reg]);
            }
        }
    }
    __syncthreads();
    {
        #pragma unroll
        for (int i = 0; i < 5; ++i) {
            const int idx = i * 256 + t;        // 0..1279
            const int row = idx >> 4;           // 0..79
            const int seg = idx & 15;
            const uint4 u = *(const uint4*)(&smem[row * 128 + seg * 8]);
            *(uint4*)(Pn + (size_t)(m0 + row) * 128 + seg * 8) = u;
        }
    }
}

// ---- phase 2: out[s] = w2 . relu(u[src] + v[dst] + b1) ----
// grid = 7813 (x32 samples, last block clamped), block = 256.
// 8 lanes/sample, 8 cols/lane, 16B loads.
__global__ __launch_bounds__(256) void edge_mlp_kernel(
    const unsigned short* __restrict__ Pn,
    const int*   __restrict__ ts,     // train_sample, int32
    const float* __restrict__ b1,     // (64)
    const float* __restrict__ w2,     // (64)
    float* __restrict__ out)          // (250000)
{
    const int t  = threadIdx.x;
    const int sr = blockIdx.x * 32 + (t >> 3);
    const int s  = min(sr, NS - 1);
    const int l  = t & 7;
    const int j  = l * 8;

    const int2 e = ((const int2*)ts)[s];
    const uint4 uu = *(const uint4*)(Pn + (size_t)e.x * 128 + j);
    const uint4 vv = *(const uint4*)(Pn + (size_t)e.y * 128 + 64 + j);
    const float4 b0 = *(const float4*)(b1 + j);
    const float4 b4 = *(const float4*)(b1 + j + 4);
    const float4 w0 = *(const float4*)(w2 + j);
    const float4 w4 = *(const float4*)(w2 + j + 4);

    float p = 0.f, x;
    x = bflo(uu.x) + bflo(vv.x) + b0.x; x = x > 0.f ? x : 0.f; p += x * w0.x;
    x = bfhi(uu.x) + bfhi(vv.x) + b0.y; x = x > 0.f ? x : 0.f; p += x * w0.y;
    x = bflo(uu.y) + bflo(vv.y) + b0.z; x = x > 0.f ? x : 0.f; p += x * w0.z;
    x = bfhi(uu.y) + bfhi(vv.y) + b0.w; x = x > 0.f ? x : 0.f; p += x * w0.w;
    x = bflo(uu.z) + bflo(vv.z) + b4.x; x = x > 0.f ? x : 0.f; p += x * w4.x;
    x = bfhi(uu.z) + bfhi(vv.z) + b4.y; x = x > 0.f ? x : 0.f; p += x * w4.y;
    x = bflo(uu.w) + bflo(vv.w) + b4.z; x = x > 0.f ? x : 0.f; p += x * w4.z;
    x = bfhi(uu.w) + bfhi(vv.w) + b4.w; x = x > 0.f ? x : 0.f; p += x * w4.w;

    p += __shfl_xor(p, 1);
    p += __shfl_xor(p, 2);
    p += __shfl_xor(p, 4);
    if (l == 0 && sr < NS) out[sr] = p;
}

extern "C" void kernel_launch(void* const* d_in, const int* in_sizes, int n_in,
                              void* d_out, int out_size, void* d_ws, size_t ws_size,
                              hipStream_t stream) {
    const float* in1 = (const float*)d_in[0];
    const float* in2 = (const float*)d_in[1];
    const int*   ts  = (const int*)  d_in[2];
    const float* w1  = (const float*)d_in[3];
    const float* b1  = (const float*)d_in[4];
    const float* w2  = (const float*)d_in[5];
    float* out = (float*)d_out;

    unsigned short* Pn = (unsigned short*)d_ws;     // 100000*128*2 = 25.6 MB
    const size_t Pbytes = (size_t)NN * 128 * sizeof(unsigned short);
    unsigned short* Bf;                             // 64 KB packed-B fragments
    if (ws_size >= Pbytes + 65536)
        Bf = (unsigned short*)((char*)d_ws + Pbytes);
    else
        Bf = (unsigned short*)d_out;   // phase-2 fully overwrites d_out after

    prep_w1_kernel<<<16, 256, 0, stream>>>(w1, Bf);
    node_gemm_mfma<<<NN / 80, 256, 0, stream>>>(in1, in2, Bf, Pn);
    edge_mlp_kernel<<<(NS + 31) / 32, 256, 0, stream>>>(Pn, ts, b1, w2, out);
}